// Round 5
// baseline (341.540 us; speedup 1.0000x reference)
//
#include <hip/hip_runtime.h>

#define NDIM 128
#define NBASES 8
#define KDIM 1152            // 8*128 (bases) + 128 (root slot)
#define GTILE 16
#define APITCH 1160          // shorts; row stride 2320 B (16B-divisible)

typedef __attribute__((ext_vector_type(8))) __bf16 bfrag;
typedef __attribute__((ext_vector_type(4))) float f32x4;

__device__ __forceinline__ float bf2f(unsigned short b) {
    return __uint_as_float(((unsigned)b) << 16);
}
__device__ __forceinline__ unsigned short f2bf(float f) {
    unsigned u = __float_as_uint(f);
    unsigned r = u + 0x7FFFu + ((u >> 16) & 1u);   // RNE
    return (unsigned short)(r >> 16);
}
__device__ __forceinline__ unsigned pack2bf(float lo, float hi) {
    return (unsigned)f2bf(lo) | ((unsigned)f2bf(hi) << 16);
}
__device__ __forceinline__ float loadF(const void* p, int idx, int isf32) {
    return isf32 ? ((const float*)p)[idx] : bf2f(((const unsigned short*)p)[idx]);
}

// ---------- dtype sniffing (R7-proven ILP version) ----------
__global__ void detect_k(const unsigned short* __restrict__ xs,
                         const int* __restrict__ ei, int* __restrict__ meta) {
    if (threadIdx.x != 0 || blockIdx.x != 0) return;
    const uint4* xv = (const uint4*)xs;
    unsigned f32m = 0;
    uint4 bx[16];
    #pragma unroll
    for (int i = 0; i < 16; ++i) bx[i] = xv[i];
    #pragma unroll
    for (int i = 0; i < 16; ++i) {
        unsigned a = bx[i].x, b = bx[i].y, c = bx[i].z, d = bx[i].w;
        f32m |= (((a & 0xFFFFu) >> 7) & 0xFFu) > 124u;
        f32m |= (((b & 0xFFFFu) >> 7) & 0xFFu) > 124u;
        f32m |= (((c & 0xFFFFu) >> 7) & 0xFFu) > 124u;
        f32m |= (((d & 0xFFFFu) >> 7) & 0xFFu) > 124u;
    }
    const uint4* ev = (const uint4*)ei;
    unsigned nzm = 0;
    for (int r = 0; r < 4; ++r) {
        uint4 be[16];
        #pragma unroll
        for (int i = 0; i < 16; ++i) be[i] = ev[r * 16 + i];
        #pragma unroll
        for (int i = 0; i < 16; ++i) nzm |= be[i].y | be[i].w;
    }
    meta[0] = f32m ? 1 : 0;
    meta[1] = nzm ? 0 : 1;
}

// merged: BT build + special-embedding copy + dst-histogram (R9-proven)
__global__ void misc_k(const void* __restrict__ basis, const void* __restrict__ root,
                       const void* __restrict__ se, const int* __restrict__ meta,
                       unsigned short* __restrict__ BT, void* __restrict__ out,
                       int scount, int sbase,
                       const int* __restrict__ ei, int E, int N, int* __restrict__ hist) {
    int t = blockIdx.x * 256 + threadIdx.x;
    int isf32 = meta[0];
    if (t < NDIM * KDIM) {
        int j = t / KDIM, k = t % KDIM;
        float v = (k < NBASES * NDIM) ? loadF(basis, k * NDIM + j, isf32)
                                      : loadF(root, (k - NBASES * NDIM) * NDIM + j, isf32);
        BT[t] = f2bf(v);
    } else {
        int u = t - NDIM * KDIM;
        if (u < scount) {
            float v = loadF(se, u, isf32);
            if (isf32) ((float*)out)[sbase + u] = v;
            else       ((unsigned short*)out)[sbase + u] = f2bf(v);
        } else {
            int e = u - scount;
            if (e < E) {
                int dst = meta[1] ? ei[2 * (E + e)] : ei[E + e];
                dst = min(max(dst, 0), N - 1);
                atomicAdd(&hist[dst], 1);
            }
        }
    }
}

// ---------- hierarchical exclusive scan (R9-proven: consumers add bpre) ----------
__global__ void scanA_k(const int* __restrict__ hist, int N,
                        int* __restrict__ offsets, int* __restrict__ bsum) {
    __shared__ int s[1024];
    int tid = threadIdx.x;
    int idx = blockIdx.x * 1024 + tid;
    int v = (idx < N) ? hist[idx] : 0;
    s[tid] = v;
    __syncthreads();
    for (int off = 1; off < 1024; off <<= 1) {
        int t = 0;
        if (tid >= off) t = s[tid - off];
        __syncthreads();
        if (tid >= off) s[tid] += t;
        __syncthreads();
    }
    if (idx < N) offsets[idx] = s[tid] - v;           // exclusive within block
    if (tid == 1023) bsum[blockIdx.x] = s[1023];
}
__global__ void scanB_k(const int* __restrict__ bsum, int NB, int N,
                        int* __restrict__ bpre, int* __restrict__ offsets) {
    __shared__ int s[64];
    int tid = threadIdx.x;
    int v = (tid < NB) ? bsum[tid] : 0;
    s[tid] = v;
    __syncthreads();
    for (int off = 1; off < 64; off <<= 1) {
        int t = 0;
        if (tid >= off) t = s[tid - off];
        __syncthreads();
        if (tid >= off) s[tid] += t;
        __syncthreads();
    }
    if (tid < NB) bpre[tid] = s[tid] - v;
    if (tid == NB - 1) offsets[N] = s[tid];           // grand total (absolute)
}

__global__ void scatter_k(const int* __restrict__ ei, const int* __restrict__ et,
                          int E, int N, const int* __restrict__ meta,
                          const int* __restrict__ offsets, const int* __restrict__ bpre,
                          int* __restrict__ cursor, int* __restrict__ sorted) {
    int e = blockIdx.x * 256 + threadIdx.x;
    if (e >= E) return;
    int i64 = meta[1];
    int src = i64 ? ei[2 * e] : ei[e];
    int dst = i64 ? ei[2 * (E + e)] : ei[E + e];
    int rel = i64 ? et[2 * e] : et[e];
    src = min(max(src, 0), N - 1);
    dst = min(max(dst, 0), N - 1);
    rel = rel & 63;
    int pos = offsets[dst] + bpre[dst >> 10] + atomicAdd(&cursor[dst], 1);
    sorted[pos] = src | (rel << 16);
}

// ---------- main fused kernel ----------
// R12 = R11 with ONE change: __launch_bounds__(1024,8) -> (1024,4).
// Diagnosis: WRITE_SIZE trail (25 MB R7 -> 50 MB R8 -> 63 MB R11) = scratch
// spill in the hot loop. Live set (acc[8][4] + depth-2 pipeline + weights)
// needs ~80 VGPR; the (1024,8) bound capped at 64 -> per-iteration spill.
// (1024,4) gives 128 VGPR/wave; measured occupancy was ~17.7/32 waves anyway,
// so capping residency at 16 waves/CU costs ~nothing.
__global__ __launch_bounds__(1024, 4) void rgcn_main_k(
    const void* __restrict__ x, const void* __restrict__ comp,
    const void* __restrict__ bias, const unsigned short* __restrict__ BT,
    const int* __restrict__ meta, const int* __restrict__ offsets,
    const int* __restrict__ bpre,
    const int* __restrict__ sorted, void* __restrict__ out, int N)
{
    __shared__ alignas(16) unsigned short A_lds[GTILE * APITCH];   // 37120 B
    __shared__ alignas(16) float comp_lds[48 * NBASES];            // [rel][basis], 1536 B
    __shared__ int cnt_lds[GTILE * 48];                            // per-wave rel counts, 3072 B
    const int tid  = threadIdx.x;
    const int lane = tid & 63;
    const int wave = tid >> 6;
    const int isf32 = meta[0];

    for (int t = tid; t < 48 * NBASES; t += 1024)
        comp_lds[t] = loadF(comp, t, isf32);
    __syncthreads();

    const int nodeBase = blockIdx.x * GTILE;
    const int dl = lane & 31;    // dim lane: dims dl*4..dl*4+3
    const int eg = lane >> 5;    // edge group 0/1; owns bases 4*eg..4*eg+3

    {   // ---- Phase A: this wave's node ----
        const int n = nodeBase + wave;
        // acc[j][i]: j<4 -> basis 4*eg+j (own); j>=4 -> basis 4*(1^eg)+(j-4) (partner's)
        float acc[8][4];
        #pragma unroll
        for (int j = 0; j < 8; ++j)
            #pragma unroll
            for (int i = 0; i < 4; ++i) acc[j][i] = 0.f;

        int* cnt_row = &cnt_lds[wave * 48];

        if (n < N) {
            const int start = offsets[n] + bpre[n >> 10];
            const int idx1  = n + 1;
            const int end   = offsets[idx1] + ((idx1 < N) ? bpre[idx1 >> 10] : 0);

            // pass 1: per-relation counts via wave-local LDS histogram (R8-proven)
            if (lane < 48) cnt_row[lane] = 0;
            for (int c = start + lane; c < end; c += 64)
                atomicAdd(&cnt_row[(sorted[c] >> 16) & 63], 1);
            if (lane < 48) {
                float nv = __builtin_amdgcn_rcpf(fmaxf((float)cnt_row[lane], 1.0f));
                cnt_row[lane] = __float_as_int(nv);
            }

            // pass 2: gather + accumulate (R8-proven structure, rotation depth 2)
            if (!isf32) {
                const unsigned short* xh = (const unsigned short*)x;
                if (start < end) {
                    int i0 = start + eg;
                    unsigned q0 = (i0 < end) ? (unsigned)sorted[i0] : 0u;
                    int i1 = start + 2 + eg;
                    unsigned q1 = (i1 < end) ? (unsigned)sorted[i1] : 0u;
                    uint2 xa0 = *(const uint2*)(xh + (size_t)(q0 & 0xFFFFu) * NDIM + dl * 4);
                    uint2 xa1 = *(const uint2*)(xh + (size_t)(q1 & 0xFFFFu) * NDIM + dl * 4);
                    int i2 = start + 4 + eg;
                    unsigned q2 = (i2 < end) ? (unsigned)sorted[i2] : 0u;
                    for (int c = start; c < end; c += 2) {
                        // issue next x-row load (2 ahead) + prefetch next sorted entry
                        uint2 xa2 = *(const uint2*)(xh + (size_t)(q2 & 0xFFFFu) * NDIM + dl * 4);
                        int i3 = c + 6 + eg;
                        unsigned q3 = (i3 < end) ? (unsigned)sorted[i3] : 0u;
                        // compute current edge (c + eg) with xa0/q0
                        bool act = (c + eg) < end;
                        int rel = (int)((q0 >> 16) & 63u);
                        float norm = act ? __int_as_float(cnt_row[rel]) : 0.f;
                        f32x4 cwA = *(const f32x4*)&comp_lds[rel * NBASES + 4 * eg];
                        f32x4 cwB = *(const f32x4*)&comp_lds[rel * NBASES + 4 * (1 ^ eg)];
                        float w[8];
                        #pragma unroll
                        for (int j = 0; j < 4; ++j) { w[j] = cwA[j] * norm; w[4 + j] = cwB[j] * norm; }
                        float xv_[4];
                        xv_[0] = __uint_as_float(xa0.x << 16);
                        xv_[1] = __uint_as_float(xa0.x & 0xFFFF0000u);
                        xv_[2] = __uint_as_float(xa0.y << 16);
                        xv_[3] = __uint_as_float(xa0.y & 0xFFFF0000u);
                        #pragma unroll
                        for (int j = 0; j < 8; ++j)
                            #pragma unroll
                            for (int i = 0; i < 4; ++i) acc[j][i] += w[j] * xv_[i];
                        q0 = q1; q1 = q2; q2 = q3;
                        xa0 = xa1; xa1 = xa2;
                    }
                }
            } else {
                const float* xfp = (const float*)x;
                for (int c = start; c < end; c += 2) {
                    bool act = (c + eg) < end;
                    unsigned q = act ? (unsigned)sorted[c + eg] : 0u;
                    int rel = (int)((q >> 16) & 63u);
                    float norm = act ? __int_as_float(cnt_row[rel]) : 0.f;
                    f32x4 cwA = *(const f32x4*)&comp_lds[rel * NBASES + 4 * eg];
                    f32x4 cwB = *(const f32x4*)&comp_lds[rel * NBASES + 4 * (1 ^ eg)];
                    float w[8];
                    #pragma unroll
                    for (int j = 0; j < 4; ++j) { w[j] = cwA[j] * norm; w[4 + j] = cwB[j] * norm; }
                    f32x4 xv = *(const f32x4*)(xfp + (size_t)(q & 0xFFFFu) * NDIM + dl * 4);
                    #pragma unroll
                    for (int j = 0; j < 8; ++j)
                        #pragma unroll
                        for (int i = 0; i < 4; ++i) acc[j][i] += w[j] * xv[i];
                }
            }
        }

        // reduce-scatter across the two edge groups (R8-proven): partner's
        // acc[4+b] are the partials for THIS lane's own bases.
        unsigned short* row = &A_lds[wave * APITCH];
        #pragma unroll
        for (int b = 0; b < 4; ++b) {
            float f0 = acc[b][0] + __shfl_xor(acc[4 + b][0], 32);
            float f1 = acc[b][1] + __shfl_xor(acc[4 + b][1], 32);
            float f2 = acc[b][2] + __shfl_xor(acc[4 + b][2], 32);
            float f3 = acc[b][3] + __shfl_xor(acc[4 + b][3], 32);
            uint2 p;
            p.x = pack2bf(f0, f1);
            p.y = pack2bf(f2, f3);
            *(uint2*)(row + (4 * eg + b) * NDIM + dl * 4) = p;
        }
        if (eg == 0) {   // root slot: node's own embedding
            uint2 xr = {0, 0};
            if (n < N) {
                if (!isf32) {
                    xr = *(const uint2*)((const unsigned short*)x + (size_t)n * NDIM + dl * 4);
                } else {
                    const float* xf = (const float*)x + (size_t)n * NDIM + dl * 4;
                    xr.x = pack2bf(xf[0], xf[1]);
                    xr.y = pack2bf(xf[2], xf[3]);
                }
            }
            *(uint2*)(row + NBASES * NDIM + dl * 4) = xr;
        }
    }
    __syncthreads();

    // ---- Phase B: [16,1152] @ [1152,128], waves 0..3, 32 cols each ----
    if (wave < 4) {
        const int m = lane & 15;
        const int q = lane >> 4;
        f32x4 C0 = {0,0,0,0}, C1 = {0,0,0,0};
        const unsigned short* arow = &A_lds[m * APITCH];
        const int jb = wave * 32;
        for (int ks = 0; ks < KDIM / 32; ++ks) {
            int k = ks * 32 + q * 8;
            bfrag a  = *(const bfrag*)(arow + k);
            bfrag b0 = *(const bfrag*)(BT + (size_t)(jb +  0 + m) * KDIM + k);
            bfrag b1 = *(const bfrag*)(BT + (size_t)(jb + 16 + m) * KDIM + k);
            C0 = __builtin_amdgcn_mfma_f32_16x16x32_bf16(a, b0, C0, 0, 0, 0);
            C1 = __builtin_amdgcn_mfma_f32_16x16x32_bf16(a, b1, C1, 0, 0, 0);
        }
        // C/D layout (m89/m91): col = lane&15, row = (lane>>4)*4 + reg
        #pragma unroll
        for (int t = 0; t < 2; ++t) {
            f32x4 Ct = t ? C1 : C0;
            int j = jb + t * 16 + m;
            float bj = loadF(bias, j, isf32);
            #pragma unroll
            for (int r = 0; r < 4; ++r) {
                int n = nodeBase + q * 4 + r;
                if (n < N) {
                    float v = Ct[r] + bj;
                    if (isf32) ((float*)out)[(size_t)n * NDIM + j] = v;
                    else       ((unsigned short*)out)[(size_t)n * NDIM + j] = f2bf(v);
                }
            }
        }
    }
}

extern "C" void kernel_launch(void* const* d_in, const int* in_sizes, int n_in,
                              void* d_out, int out_size, void* d_ws, size_t ws_size,
                              hipStream_t stream) {
    const int* ei = (const int*)d_in[0];
    const int* et = (const int*)d_in[1];

    const int E = in_sizes[1];
    const int N = in_sizes[2] / NDIM;
    const int S = in_sizes[7] / NDIM;
    const int NB = (N + 1023) / 1024;

    // workspace layout — ~3.30 MB
    char* ws = (char*)d_ws;
    size_t off = 0;
    int* meta    = (int*)(ws + off); off += 16;
    int* hist    = (int*)(ws + off); off += (size_t)N * 4;
    int* cursor  = (int*)(ws + off); off += (size_t)N * 4;
    int* offsets = (int*)(ws + off); off = (off + (size_t)(N + 1) * 4 + 15) & ~(size_t)15;
    int* bsum    = (int*)(ws + off); off += 64 * 4;
    int* bpre    = (int*)(ws + off); off += 64 * 4;
    unsigned short* BT = (unsigned short*)(ws + off); off += (size_t)NDIM * KDIM * 2;
    int* sorted  = (int*)(ws + off); off += (size_t)E * 4;

    hipMemsetAsync(hist, 0, (size_t)2 * N * 4, stream);   // hist + cursor

    detect_k<<<1, 64, 0, stream>>>((const unsigned short*)d_in[2], ei, meta);
    {
        int T = NDIM * KDIM + S * NDIM + E;
        misc_k<<<(T + 255) / 256, 256, 0, stream>>>(
            d_in[3], d_in[5], d_in[7], meta, BT, d_out, S * NDIM, N * NDIM,
            ei, E, N, hist);
    }
    scanA_k<<<NB, 1024, 0, stream>>>(hist, N, offsets, bsum);
    scanB_k<<<1, 64, 0, stream>>>(bsum, NB, N, bpre, offsets);
    scatter_k<<<(E + 255) / 256, 256, 0, stream>>>(ei, et, E, N, meta, offsets, bpre, cursor, sorted);
    rgcn_main_k<<<(N + GTILE - 1) / GTILE, 1024, 0, stream>>>(d_in[2], d_in[4], d_in[6], BT,
                                                              meta, offsets, bpre, sorted, d_out, N);
}

// Round 6
// 324.663 us; speedup vs baseline: 1.0520x; 1.0520x over previous
//
#include <hip/hip_runtime.h>

#define NDIM 128
#define NBASES 8
#define KDIM 1152            // 8*128 (bases) + 128 (root slot)
#define GTILE 16
#define APITCH 1160          // shorts; row stride 2320 B (16B-divisible)

typedef __attribute__((ext_vector_type(8))) __bf16 bfrag;
typedef __attribute__((ext_vector_type(4))) float f32x4;

__device__ __forceinline__ float bf2f(unsigned short b) {
    return __uint_as_float(((unsigned)b) << 16);
}
__device__ __forceinline__ unsigned short f2bf(float f) {
    unsigned u = __float_as_uint(f);
    unsigned r = u + 0x7FFFu + ((u >> 16) & 1u);   // RNE
    return (unsigned short)(r >> 16);
}
__device__ __forceinline__ unsigned pack2bf(float lo, float hi) {
    return (unsigned)f2bf(lo) | ((unsigned)f2bf(hi) << 16);
}
__device__ __forceinline__ float loadF(const void* p, int idx, int isf32) {
    return isf32 ? ((const float*)p)[idx] : bf2f(((const unsigned short*)p)[idx]);
}

// ---------- dtype sniffing (R7-proven ILP version) ----------
__global__ void detect_k(const unsigned short* __restrict__ xs,
                         const int* __restrict__ ei, int* __restrict__ meta) {
    if (threadIdx.x != 0 || blockIdx.x != 0) return;
    const uint4* xv = (const uint4*)xs;
    unsigned f32m = 0;
    uint4 bx[16];
    #pragma unroll
    for (int i = 0; i < 16; ++i) bx[i] = xv[i];
    #pragma unroll
    for (int i = 0; i < 16; ++i) {
        unsigned a = bx[i].x, b = bx[i].y, c = bx[i].z, d = bx[i].w;
        f32m |= (((a & 0xFFFFu) >> 7) & 0xFFu) > 124u;
        f32m |= (((b & 0xFFFFu) >> 7) & 0xFFu) > 124u;
        f32m |= (((c & 0xFFFFu) >> 7) & 0xFFu) > 124u;
        f32m |= (((d & 0xFFFFu) >> 7) & 0xFFu) > 124u;
    }
    const uint4* ev = (const uint4*)ei;
    unsigned nzm = 0;
    for (int r = 0; r < 4; ++r) {
        uint4 be[16];
        #pragma unroll
        for (int i = 0; i < 16; ++i) be[i] = ev[r * 16 + i];
        #pragma unroll
        for (int i = 0; i < 16; ++i) nzm |= be[i].y | be[i].w;
    }
    meta[0] = f32m ? 1 : 0;
    meta[1] = nzm ? 0 : 1;
}

// merged: BT build + special-embedding copy + dst-histogram (R9-proven)
__global__ void misc_k(const void* __restrict__ basis, const void* __restrict__ root,
                       const void* __restrict__ se, const int* __restrict__ meta,
                       unsigned short* __restrict__ BT, void* __restrict__ out,
                       int scount, int sbase,
                       const int* __restrict__ ei, int E, int N, int* __restrict__ hist) {
    int t = blockIdx.x * 256 + threadIdx.x;
    int isf32 = meta[0];
    if (t < NDIM * KDIM) {
        int j = t / KDIM, k = t % KDIM;
        float v = (k < NBASES * NDIM) ? loadF(basis, k * NDIM + j, isf32)
                                      : loadF(root, (k - NBASES * NDIM) * NDIM + j, isf32);
        BT[t] = f2bf(v);
    } else {
        int u = t - NDIM * KDIM;
        if (u < scount) {
            float v = loadF(se, u, isf32);
            if (isf32) ((float*)out)[sbase + u] = v;
            else       ((unsigned short*)out)[sbase + u] = f2bf(v);
        } else {
            int e = u - scount;
            if (e < E) {
                int dst = meta[1] ? ei[2 * (E + e)] : ei[E + e];
                dst = min(max(dst, 0), N - 1);
                atomicAdd(&hist[dst], 1);
            }
        }
    }
}

// ---------- hierarchical exclusive scan (R9-proven: consumers add bpre) ----------
__global__ void scanA_k(const int* __restrict__ hist, int N,
                        int* __restrict__ offsets, int* __restrict__ bsum) {
    __shared__ int s[1024];
    int tid = threadIdx.x;
    int idx = blockIdx.x * 1024 + tid;
    int v = (idx < N) ? hist[idx] : 0;
    s[tid] = v;
    __syncthreads();
    for (int off = 1; off < 1024; off <<= 1) {
        int t = 0;
        if (tid >= off) t = s[tid - off];
        __syncthreads();
        if (tid >= off) s[tid] += t;
        __syncthreads();
    }
    if (idx < N) offsets[idx] = s[tid] - v;           // exclusive within block
    if (tid == 1023) bsum[blockIdx.x] = s[1023];
}
__global__ void scanB_k(const int* __restrict__ bsum, int NB, int N,
                        int* __restrict__ bpre, int* __restrict__ offsets) {
    __shared__ int s[64];
    int tid = threadIdx.x;
    int v = (tid < NB) ? bsum[tid] : 0;
    s[tid] = v;
    __syncthreads();
    for (int off = 1; off < 64; off <<= 1) {
        int t = 0;
        if (tid >= off) t = s[tid - off];
        __syncthreads();
        if (tid >= off) s[tid] += t;
        __syncthreads();
    }
    if (tid < NB) bpre[tid] = s[tid] - v;
    if (tid == NB - 1) offsets[N] = s[tid];           // grand total (absolute)
}

__global__ void scatter_k(const int* __restrict__ ei, const int* __restrict__ et,
                          int E, int N, const int* __restrict__ meta,
                          const int* __restrict__ offsets, const int* __restrict__ bpre,
                          int* __restrict__ cursor, int* __restrict__ sorted) {
    int e = blockIdx.x * 256 + threadIdx.x;
    if (e >= E) return;
    int i64 = meta[1];
    int src = i64 ? ei[2 * e] : ei[e];
    int dst = i64 ? ei[2 * (E + e)] : ei[E + e];
    int rel = i64 ? et[2 * e] : et[e];
    src = min(max(src, 0), N - 1);
    dst = min(max(dst, 0), N - 1);
    rel = rel & 63;
    int pos = offsets[dst] + bpre[dst >> 10] + atomicAdd(&cursor[dst], 1);
    sorted[pos] = src | (rel << 16);
}

// ---------- main fused kernel ----------
// R13: lean Phase A. Each lane keeps ONLY its own 4 bases (acc[4][4], 16 VGPR,
// was 32) and processes BOTH edges of each pair for those bases: partner
// edge's q/x arrive via 3 shfl_xor(.,32); second weight set from LDS. Same
// 32 useful FMAs/iter; epilogue reduce eliminated. Live set ~56 VGPR ->
// fits the (1024,8) 64-reg budget spill-free at the 32-wave/CU ceiling
// (R12 proved: >64 VGPR halves residency; spills showed in WRITE_SIZE).
// Depth-2 gather pipeline kept. Phase B (MFMA) unchanged.
__global__ __launch_bounds__(1024, 8) void rgcn_main_k(
    const void* __restrict__ x, const void* __restrict__ comp,
    const void* __restrict__ bias, const unsigned short* __restrict__ BT,
    const int* __restrict__ meta, const int* __restrict__ offsets,
    const int* __restrict__ bpre,
    const int* __restrict__ sorted, void* __restrict__ out, int N)
{
    __shared__ alignas(16) unsigned short A_lds[GTILE * APITCH];   // 37120 B
    __shared__ alignas(16) float comp_lds[48 * NBASES];            // [rel][basis], 1536 B
    __shared__ int cnt_lds[GTILE * 48];                            // per-wave rel counts, 3072 B
    const int tid  = threadIdx.x;
    const int lane = tid & 63;
    const int wave = tid >> 6;
    const int isf32 = meta[0];

    for (int t = tid; t < 48 * NBASES; t += 1024)
        comp_lds[t] = loadF(comp, t, isf32);
    __syncthreads();

    const int nodeBase = blockIdx.x * GTILE;
    const int dl = lane & 31;    // dim lane: dims dl*4..dl*4+3
    const int eg = lane >> 5;    // edge group 0/1; owns bases 4*eg..4*eg+3

    {   // ---- Phase A: this wave's node ----
        const int n = nodeBase + wave;
        float acc[4][4];         // own 4 bases x 4 dims — complete sums
        #pragma unroll
        for (int b = 0; b < 4; ++b)
            #pragma unroll
            for (int i = 0; i < 4; ++i) acc[b][i] = 0.f;

        int* cnt_row = &cnt_lds[wave * 48];

        if (n < N) {
            const int start = offsets[n] + bpre[n >> 10];
            const int idx1  = n + 1;
            const int end   = offsets[idx1] + ((idx1 < N) ? bpre[idx1 >> 10] : 0);

            // pass 1: per-relation counts via wave-local LDS histogram (proven)
            if (lane < 48) cnt_row[lane] = 0;
            for (int c = start + lane; c < end; c += 64)
                atomicAdd(&cnt_row[(sorted[c] >> 16) & 63], 1);
            if (lane < 48) {
                float nv = __builtin_amdgcn_rcpf(fmaxf((float)cnt_row[lane], 1.0f));
                cnt_row[lane] = __float_as_int(nv);
            }

            // pass 2: gather + accumulate; own edge loaded, partner via shfl_xor
            if (!isf32) {
                const unsigned short* xh = (const unsigned short*)x;
                if (start < end) {
                    int i0 = start + eg;
                    unsigned q0 = (i0 < end) ? (unsigned)sorted[i0] : 0u;
                    int i1 = start + 2 + eg;
                    unsigned q1 = (i1 < end) ? (unsigned)sorted[i1] : 0u;
                    uint2 xa0 = *(const uint2*)(xh + (size_t)(q0 & 0xFFFFu) * NDIM + dl * 4);
                    uint2 xa1 = *(const uint2*)(xh + (size_t)(q1 & 0xFFFFu) * NDIM + dl * 4);
                    int i2 = start + 4 + eg;
                    unsigned q2 = (i2 < end) ? (unsigned)sorted[i2] : 0u;
                    for (int c = start; c < end; c += 2) {
                        // issue next x-row load (2 ahead) + prefetch next sorted entry
                        uint2 xa2 = *(const uint2*)(xh + (size_t)(q2 & 0xFFFFu) * NDIM + dl * 4);
                        int i3 = c + 6 + eg;
                        unsigned q3 = (i3 < end) ? (unsigned)sorted[i3] : 0u;

                        // current pair: own edge (c+eg) in regs; partner via shfl
                        bool act_o = (c + eg) < end;
                        bool act_p = (c + (1 ^ eg)) < end;
                        unsigned qp = (unsigned)__shfl_xor((int)q0, 32);
                        int rel_o = (int)((q0 >> 16) & 63u);
                        int rel_p = (int)((qp >> 16) & 63u);
                        float nrm_o = act_o ? __int_as_float(cnt_row[rel_o]) : 0.f;
                        float nrm_p = act_p ? __int_as_float(cnt_row[rel_p]) : 0.f;
                        f32x4 cw_o = *(const f32x4*)&comp_lds[rel_o * NBASES + 4 * eg];
                        f32x4 cw_p = *(const f32x4*)&comp_lds[rel_p * NBASES + 4 * eg];
                        unsigned px = (unsigned)__shfl_xor((int)xa0.x, 32);
                        unsigned py = (unsigned)__shfl_xor((int)xa0.y, 32);
                        float xo[4], xq[4];
                        xo[0] = __uint_as_float(xa0.x << 16)          * nrm_o;
                        xo[1] = __uint_as_float(xa0.x & 0xFFFF0000u)  * nrm_o;
                        xo[2] = __uint_as_float(xa0.y << 16)          * nrm_o;
                        xo[3] = __uint_as_float(xa0.y & 0xFFFF0000u)  * nrm_o;
                        xq[0] = __uint_as_float(px << 16)             * nrm_p;
                        xq[1] = __uint_as_float(px & 0xFFFF0000u)     * nrm_p;
                        xq[2] = __uint_as_float(py << 16)             * nrm_p;
                        xq[3] = __uint_as_float(py & 0xFFFF0000u)     * nrm_p;
                        #pragma unroll
                        for (int b = 0; b < 4; ++b)
                            #pragma unroll
                            for (int i = 0; i < 4; ++i)
                                acc[b][i] += cw_o[b] * xo[i] + cw_p[b] * xq[i];
                        q0 = q1; q1 = q2; q2 = q3;
                        xa0 = xa1; xa1 = xa2;
                    }
                }
            } else {
                const float* xfp = (const float*)x;
                for (int c = start; c < end; c += 2) {
                    bool act_o = (c + eg) < end;
                    bool act_p = (c + (1 ^ eg)) < end;
                    int io = c + eg;
                    unsigned q0 = (io < end) ? (unsigned)sorted[io] : 0u;
                    unsigned qp = (unsigned)__shfl_xor((int)q0, 32);
                    int rel_o = (int)((q0 >> 16) & 63u);
                    int rel_p = (int)((qp >> 16) & 63u);
                    float nrm_o = act_o ? __int_as_float(cnt_row[rel_o]) : 0.f;
                    float nrm_p = act_p ? __int_as_float(cnt_row[rel_p]) : 0.f;
                    f32x4 cw_o = *(const f32x4*)&comp_lds[rel_o * NBASES + 4 * eg];
                    f32x4 cw_p = *(const f32x4*)&comp_lds[rel_p * NBASES + 4 * eg];
                    f32x4 xv = *(const f32x4*)(xfp + (size_t)(q0 & 0xFFFFu) * NDIM + dl * 4);
                    float xo[4], xq[4];
                    #pragma unroll
                    for (int i = 0; i < 4; ++i) {
                        xo[i] = xv[i] * nrm_o;
                        xq[i] = __shfl_xor(xv[i], 32) * nrm_p;
                    }
                    #pragma unroll
                    for (int b = 0; b < 4; ++b)
                        #pragma unroll
                        for (int i = 0; i < 4; ++i)
                            acc[b][i] += cw_o[b] * xo[i] + cw_p[b] * xq[i];
                }
            }
        }

        // epilogue: each lane's acc is complete — write own 4 bases directly
        unsigned short* row = &A_lds[wave * APITCH];
        #pragma unroll
        for (int b = 0; b < 4; ++b) {
            uint2 p;
            p.x = pack2bf(acc[b][0], acc[b][1]);
            p.y = pack2bf(acc[b][2], acc[b][3]);
            *(uint2*)(row + (4 * eg + b) * NDIM + dl * 4) = p;
        }
        if (eg == 0) {   // root slot: node's own embedding
            uint2 xr = {0, 0};
            if (n < N) {
                if (!isf32) {
                    xr = *(const uint2*)((const unsigned short*)x + (size_t)n * NDIM + dl * 4);
                } else {
                    const float* xf = (const float*)x + (size_t)n * NDIM + dl * 4;
                    xr.x = pack2bf(xf[0], xf[1]);
                    xr.y = pack2bf(xf[2], xf[3]);
                }
            }
            *(uint2*)(row + NBASES * NDIM + dl * 4) = xr;
        }
    }
    __syncthreads();

    // ---- Phase B: [16,1152] @ [1152,128], waves 0..3, 32 cols each ----
    if (wave < 4) {
        const int m = lane & 15;
        const int q = lane >> 4;
        f32x4 C0 = {0,0,0,0}, C1 = {0,0,0,0};
        const unsigned short* arow = &A_lds[m * APITCH];
        const int jb = wave * 32;
        for (int ks = 0; ks < KDIM / 32; ++ks) {
            int k = ks * 32 + q * 8;
            bfrag a  = *(const bfrag*)(arow + k);
            bfrag b0 = *(const bfrag*)(BT + (size_t)(jb +  0 + m) * KDIM + k);
            bfrag b1 = *(const bfrag*)(BT + (size_t)(jb + 16 + m) * KDIM + k);
            C0 = __builtin_amdgcn_mfma_f32_16x16x32_bf16(a, b0, C0, 0, 0, 0);
            C1 = __builtin_amdgcn_mfma_f32_16x16x32_bf16(a, b1, C1, 0, 0, 0);
        }
        // C/D layout (m89/m91): col = lane&15, row = (lane>>4)*4 + reg
        #pragma unroll
        for (int t = 0; t < 2; ++t) {
            f32x4 Ct = t ? C1 : C0;
            int j = jb + t * 16 + m;
            float bj = loadF(bias, j, isf32);
            #pragma unroll
            for (int r = 0; r < 4; ++r) {
                int n = nodeBase + q * 4 + r;
                if (n < N) {
                    float v = Ct[r] + bj;
                    if (isf32) ((float*)out)[(size_t)n * NDIM + j] = v;
                    else       ((unsigned short*)out)[(size_t)n * NDIM + j] = f2bf(v);
                }
            }
        }
    }
}

extern "C" void kernel_launch(void* const* d_in, const int* in_sizes, int n_in,
                              void* d_out, int out_size, void* d_ws, size_t ws_size,
                              hipStream_t stream) {
    const int* ei = (const int*)d_in[0];
    const int* et = (const int*)d_in[1];

    const int E = in_sizes[1];
    const int N = in_sizes[2] / NDIM;
    const int S = in_sizes[7] / NDIM;
    const int NB = (N + 1023) / 1024;

    // workspace layout — ~3.30 MB
    char* ws = (char*)d_ws;
    size_t off = 0;
    int* meta    = (int*)(ws + off); off += 16;
    int* hist    = (int*)(ws + off); off += (size_t)N * 4;
    int* cursor  = (int*)(ws + off); off += (size_t)N * 4;
    int* offsets = (int*)(ws + off); off = (off + (size_t)(N + 1) * 4 + 15) & ~(size_t)15;
    int* bsum    = (int*)(ws + off); off += 64 * 4;
    int* bpre    = (int*)(ws + off); off += 64 * 4;
    unsigned short* BT = (unsigned short*)(ws + off); off += (size_t)NDIM * KDIM * 2;
    int* sorted  = (int*)(ws + off); off += (size_t)E * 4;

    hipMemsetAsync(hist, 0, (size_t)2 * N * 4, stream);   // hist + cursor

    detect_k<<<1, 64, 0, stream>>>((const unsigned short*)d_in[2], ei, meta);
    {
        int T = NDIM * KDIM + S * NDIM + E;
        misc_k<<<(T + 255) / 256, 256, 0, stream>>>(
            d_in[3], d_in[5], d_in[7], meta, BT, d_out, S * NDIM, N * NDIM,
            ei, E, N, hist);
    }
    scanA_k<<<NB, 1024, 0, stream>>>(hist, N, offsets, bsum);
    scanB_k<<<1, 64, 0, stream>>>(bsum, NB, N, bpre, offsets);
    scatter_k<<<(E + 255) / 256, 256, 0, stream>>>(ei, et, E, N, meta, offsets, bpre, cursor, sorted);
    rgcn_main_k<<<(N + GTILE - 1) / GTILE, 1024, 0, stream>>>(d_in[2], d_in[4], d_in[6], BT,
                                                              meta, offsets, bpre, sorted, d_out, N);
}